// Round 1
// baseline (165.455 us; speedup 1.0000x reference)
//
#include <hip/hip_runtime.h>
#include <hip/hip_bf16.h>
#include <stdint.h>

#define IN_F 4096
#define OUT_F 4096
#define NG 32

typedef __attribute__((ext_vector_type(8))) short short8;
typedef __attribute__((ext_vector_type(4))) float floatx4;

// Unpack 8 nibbles per int32 -> bf16 W[n][k] row-major (B^T layout for GEMM).
__global__ __launch_bounds__(256) void dequant_kernel(
    const int* __restrict__ wp, const float* __restrict__ scale,
    const int* __restrict__ zero, __hip_bfloat16* __restrict__ Wb) {
  int p = blockIdx.x * 256 + threadIdx.x;          // 0 .. 2097151
  int row = p >> 9;                                 // 512 int32 per output row
  int g = (p >> 4) & 31;                            // 16 int32 per 128-group
  float s = scale[row * NG + g];
  float zs = (float)zero[row * NG + g] * s;
  unsigned v = (unsigned)wp[p];
  union { __hip_bfloat16 h[8]; uint4 u4; } o;
#pragma unroll
  for (int i = 0; i < 8; ++i) {
    int q = (int)((v >> (4 * i)) & 15u);
    q -= (q >= 8) ? 16 : 0;                         // signed 4-bit
    o.h[i] = __float2bfloat16((float)q * s - zs);   // (q - zero) * scale
  }
  *(uint4*)(Wb + (size_t)p * 8) = o.u4;
}

__global__ __launch_bounds__(256) void convert_kernel(
    const float* __restrict__ x, __hip_bfloat16* __restrict__ xb) {
  int i = blockIdx.x * 256 + threadIdx.x;
  float4 v = ((const float4*)x)[i];
  union { __hip_bfloat16 h[4]; uint2 u; } o;
  o.h[0] = __float2bfloat16(v.x);
  o.h[1] = __float2bfloat16(v.y);
  o.h[2] = __float2bfloat16(v.z);
  o.h[3] = __float2bfloat16(v.w);
  ((uint2*)xb)[i] = o.u;
}

// C[m][n] = sum_k A[m][k] * Bt[n][k]; A: M x K bf16, Bt: N x K bf16, C: M x N f32.
// 128x128 tile / block of 256 threads (4 waves, each 64x64 = acc[4][4] of 16x16).
#define BM 128
#define BN 128
#define BK 64

__global__ __launch_bounds__(256) void gemm_bt(
    const __hip_bfloat16* __restrict__ A, const __hip_bfloat16* __restrict__ Bt,
    float* __restrict__ C, int M, int N, int K) {
  __shared__ short Alds[BM * BK];   // [row][k], stride 64, unpadded (global_load_lds)
  __shared__ short Blds[BN * BK];

  int t = threadIdx.x;
  int wave = t >> 6, lane = t & 63;
  int wm = (wave >> 1) * 64, wn = (wave & 1) * 64;
  int r = lane & 15, quad = lane >> 4;
  int bm = blockIdx.y * BM, bn = blockIdx.x * BN;

  floatx4 acc[4][4] = {};

  const __hip_bfloat16* Ag = A + (size_t)bm * K;
  const __hip_bfloat16* Bg = Bt + (size_t)bn * K;

  for (int k0 = 0; k0 < K; k0 += BK) {
    __syncthreads();  // previous compute done before overwriting LDS
#pragma unroll
    for (int j = 0; j < 4; ++j) {
      int c = t + 256 * j;            // 16B chunk id, 8 chunks per row
      int row = c >> 3, kc = c & 7;
      const __hip_bfloat16* ga = Ag + (size_t)row * K + k0 + kc * 8;
      const __hip_bfloat16* gb = Bg + (size_t)row * K + k0 + kc * 8;
      __builtin_amdgcn_global_load_lds(
          (const __attribute__((address_space(1))) void*)ga,
          (__attribute__((address_space(3))) void*)(&Alds[c * 8]), 16, 0, 0);
      __builtin_amdgcn_global_load_lds(
          (const __attribute__((address_space(1))) void*)gb,
          (__attribute__((address_space(3))) void*)(&Blds[c * 8]), 16, 0, 0);
    }
    __syncthreads();  // implies vmcnt(0): staged data visible

#pragma unroll
    for (int ks = 0; ks < 2; ++ks) {
      int kk = ks * 32;
      short8 af[4], bf[4];
#pragma unroll
      for (int mi = 0; mi < 4; ++mi)
        af[mi] = *(const short8*)&Alds[(wm + mi * 16 + r) * BK + kk + quad * 8];
#pragma unroll
      for (int ni = 0; ni < 4; ++ni)
        bf[ni] = *(const short8*)&Blds[(wn + ni * 16 + r) * BK + kk + quad * 8];
#pragma unroll
      for (int mi = 0; mi < 4; ++mi)
#pragma unroll
        for (int ni = 0; ni < 4; ++ni)
          acc[mi][ni] = __builtin_amdgcn_mfma_f32_16x16x32_bf16(
              af[mi], bf[ni], acc[mi][ni], 0, 0, 0);
    }
  }

  // Epilogue: C/D layout col = lane&15, row = quad*4 + reg
#pragma unroll
  for (int mi = 0; mi < 4; ++mi) {
#pragma unroll
    for (int ni = 0; ni < 4; ++ni) {
#pragma unroll
      for (int i = 0; i < 4; ++i) {
        int grow = bm + wm + mi * 16 + quad * 4 + i;
        int gcol = bn + wn + ni * 16 + r;
        C[(size_t)grow * N + gcol] = acc[mi][ni][i];
      }
    }
  }
}

extern "C" void kernel_launch(void* const* d_in, const int* in_sizes, int n_in,
                              void* d_out, int out_size, void* d_ws, size_t ws_size,
                              hipStream_t stream) {
  const float* x = (const float*)d_in[0];
  const int* wp = (const int*)d_in[1];
  const float* wscale = (const float*)d_in[2];
  const int* wzero = (const int*)d_in[3];
  float* out = (float*)d_out;

  int M = in_sizes[0] / IN_F;  // 1024

  __hip_bfloat16* Wb = (__hip_bfloat16*)d_ws;
  __hip_bfloat16* Xb = (__hip_bfloat16*)((char*)d_ws + (size_t)OUT_F * IN_F * 2);

  dequant_kernel<<<(OUT_F * IN_F / 8) / 256, 256, 0, stream>>>(wp, wscale, wzero, Wb);
  convert_kernel<<<(M * IN_F / 4) / 256, 256, 0, stream>>>(x, Xb);

  dim3 grid(OUT_F / BN, M / BM);
  gemm_bt<<<grid, 256, 0, stream>>>(Xb, Wb, out, M, OUT_F, IN_F);
}

// Round 2
// 138.770 us; speedup vs baseline: 1.1923x; 1.1923x over previous
//
#include <hip/hip_runtime.h>
#include <hip/hip_bf16.h>
#include <stdint.h>

#define IN_F 4096
#define OUT_F 4096
#define NG 32

typedef __attribute__((ext_vector_type(8))) short short8;
typedef __attribute__((ext_vector_type(4))) float floatx4;

// Unpack 8 nibbles per int32 -> bf16 W[n][k] row-major (B^T layout for GEMM).
__global__ __launch_bounds__(256) void dequant_kernel(
    const int* __restrict__ wp, const float* __restrict__ scale,
    const int* __restrict__ zero, __hip_bfloat16* __restrict__ Wb) {
  int p = blockIdx.x * 256 + threadIdx.x;          // 0 .. 2097151
  int row = p >> 9;                                 // 512 int32 per output row
  int g = (p >> 4) & 31;                            // 16 int32 per 128-group
  float s = scale[row * NG + g];
  float zs = (float)zero[row * NG + g] * s;
  unsigned v = (unsigned)wp[p];
  union { __hip_bfloat16 h[8]; uint4 u4; } o;
#pragma unroll
  for (int i = 0; i < 8; ++i) {
    int q = (int)((v >> (4 * i)) & 15u);
    q -= (q >= 8) ? 16 : 0;                         // signed 4-bit
    o.h[i] = __float2bfloat16((float)q * s - zs);   // (q - zero) * scale
  }
  *(uint4*)(Wb + (size_t)p * 8) = o.u4;
}

__global__ __launch_bounds__(256) void convert_kernel(
    const float* __restrict__ x, __hip_bfloat16* __restrict__ xb) {
  int i = blockIdx.x * 256 + threadIdx.x;
  float4 v = ((const float4*)x)[i];
  union { __hip_bfloat16 h[4]; uint2 u; } o;
  o.h[0] = __float2bfloat16(v.x);
  o.h[1] = __float2bfloat16(v.y);
  o.h[2] = __float2bfloat16(v.z);
  o.h[3] = __float2bfloat16(v.w);
  ((uint2*)xb)[i] = o.u;
}

// C[m][n] = sum_k A[m][k] * Bt[n][k]; A: M x K bf16, Bt: N x K bf16.
// 128x128 tile / block of 256 threads (4 waves, each 64x64 = acc[4][4]).
// Split-K=2 over blockIdx.z: z=0 -> C0 (d_out), z=1 -> C1 (ws partial).
#define BM 128
#define BN 128
#define BK 64
#define SPLITK 2

__global__ __launch_bounds__(256) void gemm_bt(
    const __hip_bfloat16* __restrict__ A, const __hip_bfloat16* __restrict__ Bt,
    float* __restrict__ C0, float* __restrict__ C1, int M, int N, int K) {
  __shared__ short Alds[BM * BK];   // [row][k], stride 64, unpadded (global_load_lds)
  __shared__ short Blds[BN * BK];

  int t = threadIdx.x;
  int wave = t >> 6, lane = t & 63;
  int wm = (wave >> 1) * 64, wn = (wave & 1) * 64;
  int r = lane & 15, quad = lane >> 4;
  int bm = blockIdx.y * BM, bn = blockIdx.x * BN;
  int kz = blockIdx.z * (K / SPLITK);
  int kend = kz + K / SPLITK;

  floatx4 acc[4][4] = {};

  const __hip_bfloat16* Ag = A + (size_t)bm * K;
  const __hip_bfloat16* Bg = Bt + (size_t)bn * K;

  for (int k0 = kz; k0 < kend; k0 += BK) {
    __syncthreads();  // previous compute done before overwriting LDS
#pragma unroll
    for (int j = 0; j < 4; ++j) {
      int c = t + 256 * j;            // 16B chunk id, 8 chunks per row
      int row = c >> 3, kc = c & 7;
      const __hip_bfloat16* ga = Ag + (size_t)row * K + k0 + kc * 8;
      const __hip_bfloat16* gb = Bg + (size_t)row * K + k0 + kc * 8;
      __builtin_amdgcn_global_load_lds(
          (const __attribute__((address_space(1))) void*)ga,
          (__attribute__((address_space(3))) void*)(&Alds[c * 8]), 16, 0, 0);
      __builtin_amdgcn_global_load_lds(
          (const __attribute__((address_space(1))) void*)gb,
          (__attribute__((address_space(3))) void*)(&Blds[c * 8]), 16, 0, 0);
    }
    __syncthreads();  // implies vmcnt(0): staged data visible

#pragma unroll
    for (int ks = 0; ks < 2; ++ks) {
      int kk = ks * 32;
      short8 af[4], bf[4];
#pragma unroll
      for (int mi = 0; mi < 4; ++mi)
        af[mi] = *(const short8*)&Alds[(wm + mi * 16 + r) * BK + kk + quad * 8];
#pragma unroll
      for (int ni = 0; ni < 4; ++ni)
        bf[ni] = *(const short8*)&Blds[(wn + ni * 16 + r) * BK + kk + quad * 8];
#pragma unroll
      for (int mi = 0; mi < 4; ++mi)
#pragma unroll
        for (int ni = 0; ni < 4; ++ni)
          acc[mi][ni] = __builtin_amdgcn_mfma_f32_16x16x32_bf16(
              af[mi], bf[ni], acc[mi][ni], 0, 0, 0);
    }
  }

  float* C = (blockIdx.z == 0) ? C0 : C1;
  // Epilogue: C/D layout col = lane&15, row = quad*4 + reg
#pragma unroll
  for (int mi = 0; mi < 4; ++mi) {
#pragma unroll
    for (int ni = 0; ni < 4; ++ni) {
#pragma unroll
      for (int i = 0; i < 4; ++i) {
        int grow = bm + wm + mi * 16 + quad * 4 + i;
        int gcol = bn + wn + ni * 16 + r;
        C[(size_t)grow * N + gcol] = acc[mi][ni][i];
      }
    }
  }
}

__global__ __launch_bounds__(256) void reduce_kernel(
    float* __restrict__ out, const float* __restrict__ part) {
  int i = blockIdx.x * 256 + threadIdx.x;
  float4 a = ((const float4*)out)[i];
  float4 b = ((const float4*)part)[i];
  a.x += b.x; a.y += b.y; a.z += b.z; a.w += b.w;
  ((float4*)out)[i] = a;
}

extern "C" void kernel_launch(void* const* d_in, const int* in_sizes, int n_in,
                              void* d_out, int out_size, void* d_ws, size_t ws_size,
                              hipStream_t stream) {
  const float* x = (const float*)d_in[0];
  const int* wp = (const int*)d_in[1];
  const float* wscale = (const float*)d_in[2];
  const int* wzero = (const int*)d_in[3];
  float* out = (float*)d_out;

  int M = in_sizes[0] / IN_F;  // 1024

  __hip_bfloat16* Wb = (__hip_bfloat16*)d_ws;                                  // 33.5 MB
  __hip_bfloat16* Xb = (__hip_bfloat16*)((char*)d_ws + (size_t)OUT_F * IN_F * 2);  // 8.4 MB
  float* Cpart = (float*)((char*)d_ws + (size_t)OUT_F * IN_F * 2 + (size_t)M * IN_F * 2);  // 16.8 MB

  dequant_kernel<<<(OUT_F * IN_F / 8) / 256, 256, 0, stream>>>(wp, wscale, wzero, Wb);
  convert_kernel<<<(M * IN_F / 4) / 256, 256, 0, stream>>>(x, Xb);

  dim3 grid(OUT_F / BN, M / BM, SPLITK);
  gemm_bt<<<grid, 256, 0, stream>>>(Xb, Wb, out, Cpart, M, OUT_F, IN_F);

  reduce_kernel<<<(M * OUT_F / 4) / 256, 256, 0, stream>>>(out, Cpart);
}